// Round 16
// baseline (89.620 us; speedup 1.0000x reference)
//
#include <hip/hip_runtime.h>
#include <hip/hip_bf16.h>

// Problem constants (fixed by the reference)
#define Bz 8
#define Cc 256
#define HWp 23104            // 152*152
#define Kk 1024
#define BK (Bz*Kk)
#define MARGIN_F 10.0f
#define BIGF 1e30f
#define TILE 128
#define NBK 128              // buckets (hw>>8 in [0,90], padded to 128)

typedef __attribute__((ext_vector_type(8))) short bf16x8;  // 8 bf16 = 4 VGPRs
typedef __attribute__((ext_vector_type(4))) float f32x4;   // MFMA 16x16 accumulator

__device__ __forceinline__ uint pk2(float a, float b) {
    return (uint)__hip_bfloat16_raw(__float2bfloat16(a)).x
         | ((uint)__hip_bfloat16_raw(__float2bfloat16(b)).x << 16);
}

// ---------------------------------------------------------------------------
// K0: per-batch BUCKET sort (verbatim R13, proven).  bucket = hw>>8; 3
// barriers: LDS histogram -> serial prefix -> scatter via cursor atomicAdd.
// Intra-bucket order is timing-dependent but every downstream output byte is
// order-independent (each k writes only its own row; neg is atomicMin).
// Also inits neg_min and cnt (ws poisoned once, never re-poisoned; cnt ends
// each launch at 512 and is re-zeroed here -> graph-replay safe).
// ---------------------------------------------------------------------------
__global__ __launch_bounds__(1024) void bucket_sort(
    const int* __restrict__ ind, uint* __restrict__ sorted,
    unsigned* __restrict__ neg, unsigned* __restrict__ cnt)
{
    __shared__ uint cur[NBK];
    const int b = blockIdx.x, tid = threadIdx.x;
    if (tid < NBK) cur[tid] = 0;
    neg[b * Kk + tid] = __float_as_uint(BIGF);
    if (b == 0 && tid == 0) *cnt = 0u;
    __syncthreads();
    int hw = ind[b * Kk + tid];
    int bk = hw >> 8;                       // 0..90
    atomicAdd(&cur[bk], 1u);
    __syncthreads();
    if (tid == 0) {                         // exclusive prefix (serial, 128)
        uint acc = 0;
        #pragma unroll
        for (int i = 0; i < NBK; ++i) { uint c = cur[i]; cur[i] = acc; acc += c; }
    }
    __syncthreads();
    uint slot = atomicAdd(&cur[bk], 1u);    // unique slot within bucket
    sorted[b * Kk + slot] = ((uint)hw << 10) | (uint)tid;
}

// ---------------------------------------------------------------------------
// K1: sorted gather (VERBATIM R13 — R14 lesson: lanes must sweep sorted
// entries, not channels; the (16 entries x 4 planes)/instruction mapping is
// the proven-fastest).  Block = (kq, 32-ch group, b) = 16x8x8 = 1024.
// Thread t: entry kl = t>>2, octet cq = t&3; 8 independent loads/thread;
// bucket-local ordering -> near-sequential line fetches, ~24 MB total.
// Lanes (kl, cq=0..3) write ONE full 64B embr line per k, exactly once.
// ---------------------------------------------------------------------------
__global__ __launch_bounds__(256) void sorted_gather(
    const float* __restrict__ x, const uint* __restrict__ sorted,
    __hip_bfloat16* __restrict__ embr)
{
    const int kq = blockIdx.x, cg = blockIdx.y, b = blockIdx.z;
    const int c0 = cg * 32;
    const int t = threadIdx.x;
    const int kl = t >> 2, cq = t & 3;
    uint e = sorted[b * Kk + kq * 64 + kl];
    int hw = (int)(e >> 10), k = (int)(e & 1023u);
    const float* xp = x + (size_t)(b * Cc + c0 + cq * 8) * HWp + hw;
    float v[8];
    #pragma unroll
    for (int j = 0; j < 8; ++j) v[j] = xp[(size_t)j * HWp];
    uint4 o = make_uint4(pk2(v[0], v[1]), pk2(v[2], v[3]),
                         pk2(v[4], v[5]), pk2(v[6], v[7]));
    *(uint4*)((ushort*)embr + (size_t)(b * Kk + k) * Cc + c0 + cq * 8) = o;
}

// ---------------------------------------------------------------------------
// K2: Gram (verbatim R5/R13 MFMA core) + ABSORBED rownorm preamble +
// ABSORBED hinge tail (R10 pattern minus its poisons: no ssq_part scatter).
//  - preamble: one row/thread, 32x16B L2 reads in fixed col order 0..255 ->
//    every block computes bitwise-identical scl; kills rownorm kernel +
//    boundary + the scl global round-trip.
//  - tail: threadfence + atomicAdd(cnt); block seeing 511 reads neg via
//    agent-scope atomic loads (cnt RMW total order makes all prior
//    atomicMins visible) and writes the scalar.
// d2 = 200 - 2*scl_i*scl_j*Graw, clamped >= 0 BEFORE the uint-bit atomicMin
// (duplicate-index pairs = the loss signal; identical rows -> identical scl).
// ---------------------------------------------------------------------------
__global__ __launch_bounds__(256) void gram_min_hinge(
    const __hip_bfloat16* __restrict__ emb, const int* __restrict__ mask,
    unsigned* __restrict__ neg, unsigned* __restrict__ cnt,
    float* __restrict__ out)
{
    __shared__ __align__(16) short As[TILE * 64];   // 16 KB
    __shared__ __align__(16) short Bs[TILE * 64];   // 16 KB
    __shared__ float scl_i[TILE], scl_j[TILE];      // 1 KB
    __shared__ uint lastFlag;

    int b  = blockIdx.z;
    int i0 = blockIdx.y * TILE;
    int j0 = blockIdx.x * TILE;
    int tid = threadIdx.x;
    int w  = tid >> 6, l = tid & 63;
    int wr = w >> 1, wc = w & 1;          // wave's 64x64 quadrant
    int lr = l & 15, lg = l >> 4;         // lane row / k-group

    const short* E  = (const short*)emb + (size_t)b * Kk * Cc;
    const short* EA = E + (size_t)i0 * Cc;
    const short* EB = E + (size_t)j0 * Cc;

    // ---- preamble: scl for the block's 128 i-rows and 128 j-rows ---------
    {
        int m = tid >> 7;                  // 0 = i-panel, 1 = j-panel
        int r = tid & 127;
        const short* rp = (m ? EB : EA) + (size_t)r * Cc;
        float s2 = 0.f;
        #pragma unroll
        for (int c = 0; c < 32; ++c) {
            bf16x8 vv = *(const bf16x8*)(rp + c * 8);
            #pragma unroll
            for (int j = 0; j < 8; ++j) {
                float f = __uint_as_float((uint)(ushort)vv[j] << 16);
                s2 += f * f;
            }
        }
        float sc = 10.0f / fmaxf(sqrtf(s2), 1e-12f);
        if (m) scl_j[r] = sc; else scl_i[r] = sc;
    }
    // (first k-loop __syncthreads orders these writes before epilogue reads)

    // staging: instr t (=w*4+q) fills LDS rows t*8..t*8+7; lane l ->
    // row offset l/8, slot l%8; source k-chunk = (l%8) ^ (l/8).
    const int lrow = l >> 3;
    const int lsub = (l & 7) ^ lrow;

    f32x4 acc[4][4] = {};
    for (int k0 = 0; k0 < Cc; k0 += 64) {
        #pragma unroll
        for (int q = 0; q < 4; ++q) {
            int t = w * 4 + q;
            int r = t * 8 + lrow;
            __builtin_amdgcn_global_load_lds(
                (const __attribute__((address_space(1))) void*)(EA + (size_t)r * Cc + k0 + lsub * 8),
                (__attribute__((address_space(3))) void*)&As[t * 512], 16, 0, 0);
            __builtin_amdgcn_global_load_lds(
                (const __attribute__((address_space(1))) void*)(EB + (size_t)r * Cc + k0 + lsub * 8),
                (__attribute__((address_space(3))) void*)&Bs[t * 512], 16, 0, 0);
        }
        __syncthreads();

        #pragma unroll
        for (int kk = 0; kk < 2; ++kk) {
            bf16x8 af[4], bf[4];
            #pragma unroll
            for (int f = 0; f < 4; ++f) {
                int ra = wr * 64 + f * 16 + lr;
                af[f] = *(const bf16x8*)&As[ra * 64 + (((kk * 4 + lg) ^ (ra & 7)) << 3)];
                int rb = wc * 64 + f * 16 + lr;
                bf[f] = *(const bf16x8*)&Bs[rb * 64 + (((kk * 4 + lg) ^ (rb & 7)) << 3)];
            }
            #pragma unroll
            for (int fi = 0; fi < 4; ++fi)
                #pragma unroll
                for (int fj = 0; fj < 4; ++fj)
                    acc[fi][fj] = __builtin_amdgcn_mfma_f32_16x16x32_bf16(
                                      af[fi], bf[fj], acc[fi][fj], 0, 0, 0);
        }
        __syncthreads();
    }

    const int* mb = mask + b * Kk;
    float cjv[4]; int jgv[4]; bool jva[4];
    #pragma unroll
    for (int fj = 0; fj < 4; ++fj) {
        int jl = wc * 64 + fj * 16 + lr;
        jgv[fj] = j0 + jl;
        cjv[fj] = scl_j[jl];
        jva[fj] = (mb[j0 + jl] != 0);
    }
    #pragma unroll
    for (int fi = 0; fi < 4; ++fi) {
        #pragma unroll
        for (int r = 0; r < 4; ++r) {
            int il = wr * 64 + fi * 16 + 4 * lg + r;
            int ig = i0 + il;
            float ci = scl_i[il];
            float m = BIGF;
            #pragma unroll
            for (int fj = 0; fj < 4; ++fj) {
                float d2 = fmaxf(200.0f - 2.0f * ci * cjv[fj] * acc[fi][fj][r], 0.0f);
                bool ok = jva[fj] && (jgv[fj] != ig);
                m = ok ? fminf(m, d2) : m;
            }
            #pragma unroll
            for (int off = 1; off < 16; off <<= 1)
                m = fminf(m, __shfl_xor(m, off));
            if (lr == 0)
                atomicMin(&neg[b * Kk + ig], __float_as_uint(m));
        }
    }

    // ---- last-block hinge + mean ------------------------------------------
    __threadfence();                        // publish this block's atomicMins
    if (tid == 0)
        lastFlag = (atomicAdd(cnt, 1u) == 511u) ? 1u : 0u;
    __syncthreads();
    if (lastFlag) {
        float h = 0.f, v = 0.f;
        for (int i = tid; i < BK; i += 256) {
            unsigned nb = __hip_atomic_load(&neg[i], __ATOMIC_RELAXED,
                                            __HIP_MEMORY_SCOPE_AGENT);
            if (mask[i] != 0) {
                float d = sqrtf(__uint_as_float(nb));
                h += fmaxf(MARGIN_F - d, 0.f);
                v += 1.f;
            }
        }
        #pragma unroll
        for (int off = 32; off; off >>= 1) {
            h += __shfl_xor(h, off);
            v += __shfl_xor(v, off);
        }
        if (l == 0) { scl_i[w] = h; scl_i[4 + w] = v; }
        __syncthreads();
        if (tid == 0)
            out[0] = (scl_i[0] + scl_i[1] + scl_i[2] + scl_i[3])
                   / (scl_i[4] + scl_i[5] + scl_i[6] + scl_i[7]);
    }
}

// ---------------------------------------------------------------------------
extern "C" void kernel_launch(void* const* d_in, const int* in_sizes, int n_in,
                              void* d_out, int out_size, void* d_ws, size_t ws_size,
                              hipStream_t stream) {
    const float* x    = (const float*)d_in[0];   // [B,C,H,W] fp32
    const int*   ind  = (const int*)d_in[1];     // [B,K] int32
    const int*   mask = (const int*)d_in[2];     // [B,K] int32
    float* out = (float*)d_out;

    // ws layout: embr bf16 [B*K][C] (4 MB) | neg u32 [B*K] | sorted u32 [B*K]
    //            | cnt u32
    __hip_bfloat16* embr = (__hip_bfloat16*)d_ws;
    unsigned* neg    = (unsigned*)((char*)d_ws + (size_t)BK * Cc * sizeof(__hip_bfloat16));
    uint*     sorted = (uint*)(neg + BK);
    unsigned* cnt    = (unsigned*)(sorted + BK);

    bucket_sort<<<Bz, 1024, 0, stream>>>(ind, sorted, neg, cnt);
    dim3 g1(16, Cc / 32, Bz);                 // (16 kq, 8 cgroups, 8 b)
    sorted_gather<<<g1, 256, 0, stream>>>(x, sorted, embr);
    dim3 g2(Kk / TILE, Kk / TILE, Bz);        // 512 blocks
    gram_min_hinge<<<g2, 256, 0, stream>>>(embr, mask, neg, cnt, out);
}

// Round 17
// 80.504 us; speedup vs baseline: 1.1132x; 1.1132x over previous
//
#include <hip/hip_runtime.h>
#include <hip/hip_bf16.h>

// Problem constants (fixed by the reference)
#define Bz 8
#define Cc 256
#define HWp 23104            // 152*152
#define Kk 1024
#define BK (Bz*Kk)
#define MARGIN_F 10.0f
#define BIGF 1e30f
#define NBK 128              // buckets (hw>>8 in [0,90], padded to 128)

typedef __attribute__((ext_vector_type(8))) short bf16x8;  // 8 bf16 = 4 VGPRs
typedef __attribute__((ext_vector_type(4))) float f32x4;   // MFMA 16x16 accumulator

__device__ __forceinline__ uint pk2(float a, float b) {
    return (uint)__hip_bfloat16_raw(__float2bfloat16(a)).x
         | ((uint)__hip_bfloat16_raw(__float2bfloat16(b)).x << 16);
}

// ---------------------------------------------------------------------------
// K0: per-batch BUCKET sort (R13 core) + PARALLEL Hillis-Steele prefix
// (replaces the ~2us serial 128-loop by thread 0) + acc/cnt init.
// Intra-bucket order is timing-dependent but every downstream output byte is
// order-independent (each k writes only its own embr row; min is exact).
// ---------------------------------------------------------------------------
__global__ __launch_bounds__(1024) void bucket_sort(
    const int* __restrict__ ind, uint* __restrict__ sorted,
    float* __restrict__ acc, unsigned* __restrict__ cnt)
{
    __shared__ uint cur[NBK], pre[NBK];
    const int b = blockIdx.x, tid = threadIdx.x;
    if (tid < NBK) cur[tid] = 0;
    if (b == 0 && tid < 2) acc[tid] = 0.f;
    if (b == 0 && tid == 0) *cnt = 0u;
    __syncthreads();
    int hw = ind[b * Kk + tid];
    int bk = hw >> 8;                       // 0..90
    atomicAdd(&cur[bk], 1u);
    __syncthreads();
    uint mycount = (tid < NBK) ? cur[tid] : 0u;
    if (tid < NBK) pre[tid] = mycount;
    __syncthreads();
    #pragma unroll
    for (int off = 1; off < NBK; off <<= 1) {   // inclusive scan, 7 steps
        uint add = (tid < NBK && tid >= off) ? pre[tid - off] : 0u;
        __syncthreads();
        if (tid < NBK) pre[tid] += add;
        __syncthreads();
    }
    if (tid < NBK) cur[tid] = pre[tid] - mycount;   // exclusive cursor
    __syncthreads();
    uint slot = atomicAdd(&cur[bk], 1u);    // unique slot within bucket
    sorted[b * Kk + slot] = ((uint)hw << 10) | (uint)tid;
}

// ---------------------------------------------------------------------------
// K1: sorted gather (VERBATIM R13 — proven fastest mapping: lanes sweep
// sorted entries, 16 entries x 4 planes per instruction).  ~96 MB of 64B
// lines from cold HBM (733 of 1444 lines/plane), near-sequential order.
// Lanes (kl, cq=0..3) write ONE full 64B embr line per k, exactly once.
// ---------------------------------------------------------------------------
__global__ __launch_bounds__(256) void sorted_gather(
    const float* __restrict__ x, const uint* __restrict__ sorted,
    __hip_bfloat16* __restrict__ embr)
{
    const int kq = blockIdx.x, cg = blockIdx.y, b = blockIdx.z;
    const int c0 = cg * 32;
    const int t = threadIdx.x;
    const int kl = t >> 2, cq = t & 3;
    uint e = sorted[b * Kk + kq * 64 + kl];
    int hw = (int)(e >> 10), k = (int)(e & 1023u);
    const float* xp = x + (size_t)(b * Cc + c0 + cq * 8) * HWp + hw;
    float v[8];
    #pragma unroll
    for (int j = 0; j < 8; ++j) v[j] = xp[(size_t)j * HWp];
    uint4 o = make_uint4(pk2(v[0], v[1]), pk2(v[2], v[3]),
                         pk2(v[4], v[5]), pk2(v[6], v[7]));
    *(uint4*)((ushort*)embr + (size_t)(b * Kk + k) * Cc + c0 + cq * 8) = o;
}

// ---------------------------------------------------------------------------
// K2: gram + IN-BLOCK full-j min + hinge partials.  Block = (32-row i-panel,
// batch) = 256 blocks (1/CU).  A-panel LDS-resident (16 KB); B staged per
// (j-panel, k-chunk) via the proven XOR-swizzled global_load_lds.  The per-
// row min over ALL 1023 j's completes in-block -> no neg buffer, no
// atomicMin, no hinge kernel.  Tail: 2 atomicAdds/block into acc, fence,
// cnt; last block reads TWO atomics (not 8192 -- the R10/R15 poison) and
// writes out.  d2 = 200 - 2*scl_i*scl_j*G, clamped >= 0 before the min
// (duplicate-index pairs = the loss signal; identical rows -> identical scl
// since sclS is a fixed-order function of row bytes).
// ---------------------------------------------------------------------------
__global__ __launch_bounds__(256) void gram_hinge(
    const __hip_bfloat16* __restrict__ emb, const int* __restrict__ mask,
    float* __restrict__ acc, unsigned* __restrict__ cnt,
    float* __restrict__ out)
{
    __shared__ __align__(16) short As[4 * 32 * 64];   // 16 KB [chunk][row][slot]
    __shared__ __align__(16) short Bs[128 * 64];      // 16 KB
    __shared__ float sclS[Kk];                        // 4 KB
    __shared__ float lmin[4][16];                     // per-wave row mins
    __shared__ float red[8];

    const int px = blockIdx.x;            // i-panel 0..31
    const int b  = blockIdx.y;
    const int i0 = px * 32;
    const int tid = threadIdx.x, w = tid >> 6, l = tid & 63;
    const int lr = l & 15, lg = l >> 4;
    const int lrow = l >> 3, lsub = (l & 7) ^ lrow;
    const int roff = (w >> 1) * 16;       // wave-pair row group (0 or 16)
    const int jh   = (w & 1) * 4;         // wave's j-frag half (0 or 4)

    const short* E  = (const short*)emb + (size_t)b * Kk * Cc;
    const short* EA = E + (size_t)i0 * Cc;
    const int*   mb = mask + b * Kk;

    // stage A panel: 16 instrs; t = w*4+q -> chunk c=t>>2, sub s=t&3,
    // rows s*8+lrow of 32; source k-chunk lsub^lrow within chunk c.
    #pragma unroll
    for (int q = 0; q < 4; ++q) {
        int t = w * 4 + q;
        int c = t >> 2, s = t & 3;
        int r = s * 8 + lrow;
        __builtin_amdgcn_global_load_lds(
            (const __attribute__((address_space(1))) void*)(EA + (size_t)r * Cc + c * 64 + lsub * 8),
            (__attribute__((address_space(3))) void*)&As[c * 2048 + s * 512], 16, 0, 0);
    }

    // preamble: sclS for ALL 1024 rows (L2-resident embr; fixed col order ->
    // bitwise-identical scl in every block; dup rows -> identical scl).
    {
        int cq = tid & 3;
        for (int pp = 0; pp < 16; ++pp) {
            int row = pp * 64 + (tid >> 2);
            const short* rp = E + (size_t)row * Cc + cq * 64;
            float s2 = 0.f;
            #pragma unroll
            for (int i = 0; i < 8; ++i) {
                bf16x8 vv = *(const bf16x8*)(rp + i * 8);
                #pragma unroll
                for (int j = 0; j < 8; ++j) {
                    float f = __uint_as_float((uint)(ushort)vv[j] << 16);
                    s2 += f * f;
                }
            }
            s2 += __shfl_xor(s2, 1);
            s2 += __shfl_xor(s2, 2);
            if (cq == 0) sclS[row] = 10.0f / fmaxf(sqrtf(s2), 1e-12f);
        }
    }
    __syncthreads();   // As (vmcnt-drained) + sclS ready

    float minv[4] = {BIGF, BIGF, BIGF, BIGF};

    for (int jp = 0; jp < 8; ++jp) {
        f32x4 accf[4] = {};
        for (int c = 0; c < 4; ++c) {
            #pragma unroll
            for (int q = 0; q < 4; ++q) {
                int t = w * 4 + q;
                int r = jp * 128 + t * 8 + lrow;
                __builtin_amdgcn_global_load_lds(
                    (const __attribute__((address_space(1))) void*)(E + (size_t)r * Cc + c * 64 + lsub * 8),
                    (__attribute__((address_space(3))) void*)&Bs[t * 512], 16, 0, 0);
            }
            __syncthreads();
            #pragma unroll
            for (int kk = 0; kk < 2; ++kk) {
                int ra = roff + lr;
                bf16x8 af = *(const bf16x8*)&As[c * 2048 + ra * 64 + (((kk * 4 + lg) ^ (ra & 7)) << 3)];
                #pragma unroll
                for (int jj = 0; jj < 4; ++jj) {
                    int rb = (jh + jj) * 16 + lr;
                    bf16x8 bf = *(const bf16x8*)&Bs[rb * 64 + (((kk * 4 + lg) ^ (rb & 7)) << 3)];
                    accf[jj] = __builtin_amdgcn_mfma_f32_16x16x32_bf16(af, bf, accf[jj], 0, 0, 0);
                }
            }
            __syncthreads();
        }
        // fold this j-panel into the running per-row min
        #pragma unroll
        for (int jj = 0; jj < 4; ++jj) {
            int j = jp * 128 + (jh + jj) * 16 + lr;
            float cj = sclS[j];
            bool jv = (mb[j] != 0);
            #pragma unroll
            for (int r = 0; r < 4; ++r) {
                int ig = i0 + roff + lg * 4 + r;
                float d2 = fmaxf(200.0f - 2.0f * sclS[ig] * cj * accf[jj][r], 0.0f);
                bool ok = jv && (j != ig);
                minv[r] = ok ? fminf(minv[r], d2) : minv[r];
            }
        }
    }

    // reduce min over the 16 lr-lanes (cols), then across the wave pair
    #pragma unroll
    for (int off = 1; off < 16; off <<= 1)
        #pragma unroll
        for (int r = 0; r < 4; ++r)
            minv[r] = fminf(minv[r], __shfl_xor(minv[r], off));
    if (lr == 0) {
        #pragma unroll
        for (int r = 0; r < 4; ++r)
            lmin[w][lg * 4 + r] = minv[r];
    }
    __syncthreads();

    // hinge partials for the block's 32 rows (threads 0..31)
    float h = 0.f, v = 0.f;
    if (tid < 32) {
        int wp = tid >> 4;                       // row group 0/1
        float m = fminf(lmin[wp * 2][tid & 15], lmin[wp * 2 + 1][tid & 15]);
        if (mb[i0 + tid] != 0) {
            float d = sqrtf(m);
            h = fmaxf(MARGIN_F - d, 0.f);
            v = 1.f;
        }
    }
    #pragma unroll
    for (int off = 1; off < 32; off <<= 1) {
        h += __shfl_xor(h, off);
        v += __shfl_xor(v, off);
    }
    if (tid == 0) {
        atomicAdd(&acc[0], h);
        atomicAdd(&acc[1], v);
        __threadfence();                         // order acc adds before cnt
        if (atomicAdd(cnt, 1u) == (unsigned)(gridDim.x * gridDim.y - 1)) {
            float H = atomicAdd(&acc[0], 0.0f);  // coherent RMW reads (2 only)
            float V = atomicAdd(&acc[1], 0.0f);
            out[0] = H / V;
        }
    }
}

// ---------------------------------------------------------------------------
extern "C" void kernel_launch(void* const* d_in, const int* in_sizes, int n_in,
                              void* d_out, int out_size, void* d_ws, size_t ws_size,
                              hipStream_t stream) {
    const float* x    = (const float*)d_in[0];   // [B,C,H,W] fp32
    const int*   ind  = (const int*)d_in[1];     // [B,K] int32
    const int*   mask = (const int*)d_in[2];     // [B,K] int32
    float* out = (float*)d_out;

    // ws layout: embr bf16 [B*K][C] (4 MB) | sorted u32 [B*K] | acc f32[2] | cnt
    __hip_bfloat16* embr = (__hip_bfloat16*)d_ws;
    uint*     sorted = (uint*)((char*)d_ws + (size_t)BK * Cc * sizeof(__hip_bfloat16));
    float*    acc    = (float*)(sorted + BK);
    unsigned* cnt    = (unsigned*)(acc + 2);

    bucket_sort<<<Bz, 1024, 0, stream>>>(ind, sorted, acc, cnt);
    dim3 g1(16, Cc / 32, Bz);                 // (16 kq, 8 cgroups, 8 b)
    sorted_gather<<<g1, 256, 0, stream>>>(x, sorted, embr);
    dim3 g2(32, Bz);                          // (32 i-panels, 8 batches)
    gram_hinge<<<g2, 256, 0, stream>>>(embr, mask, acc, cnt, out);
}

// Round 18
// 51.173 us; speedup vs baseline: 1.7513x; 1.5732x over previous
//
#include <hip/hip_runtime.h>
#include <hip/hip_bf16.h>

// Problem constants (fixed by the reference)
#define Bz 8
#define Cc 256
#define HWp 23104            // 152*152
#define Kk 1024
#define BK (Bz*Kk)
#define MARGIN_F 10.0f
#define BIGF 1e30f
#define TILE 128
#define NBK 128              // buckets (hw>>8 in [0,90], padded to 128)

typedef __attribute__((ext_vector_type(8))) short bf16x8;  // 8 bf16 = 4 VGPRs
typedef __attribute__((ext_vector_type(4))) float f32x4;   // MFMA 16x16 accumulator

// ---------------------------------------------------------------------------
// K0: per-batch BUCKET sort (verbatim R13, proven ~1us).  bucket = hw>>8;
// LDS histogram -> serial prefix -> scatter via cursor atomicAdd.  Intra-
// bucket order is timing-dependent but every downstream output byte is
// order-independent.  Also inits neg_min (ws poisoned once only).
// ---------------------------------------------------------------------------
__global__ __launch_bounds__(1024) void bucket_sort(
    const int* __restrict__ ind, uint* __restrict__ sorted,
    unsigned* __restrict__ neg)
{
    __shared__ uint cur[NBK];
    const int b = blockIdx.x, tid = threadIdx.x;
    if (tid < NBK) cur[tid] = 0;
    neg[b * Kk + tid] = __float_as_uint(BIGF);
    __syncthreads();
    int hw = ind[b * Kk + tid];
    int bk = hw >> 8;                       // 0..90
    atomicAdd(&cur[bk], 1u);
    __syncthreads();
    if (tid == 0) {                         // exclusive prefix (serial, 128)
        uint acc = 0;
        #pragma unroll
        for (int i = 0; i < NBK; ++i) { uint c = cur[i]; cur[i] = acc; acc += c; }
    }
    __syncthreads();
    uint slot = atomicAdd(&cur[bk], 1u);    // unique slot within bucket
    sorted[b * Kk + slot] = ((uint)hw << 10) | (uint)tid;
}

// ---------------------------------------------------------------------------
// K1: sorted gather (R13 mapping, proven fastest) + FUSED ssq partials.
// Thread t: entry kl = t>>2, octet cq = t&3; 8 independent loads/thread.
// NEW (near-zero cost): thread's 8 rounded values -> partial ssq; 2x
// shfl_xor across the 4 adjacent cq-lanes -> 32-channel partial; lane cq==0
// stores ssq_part[cg][row] (written exactly once; ~4MB partial-line traffic,
// harmless).  embr writes unchanged: ONE full 64B line per k, exactly once.
// ---------------------------------------------------------------------------
__global__ __launch_bounds__(256) void sorted_gather(
    const float* __restrict__ x, const uint* __restrict__ sorted,
    __hip_bfloat16* __restrict__ embr, float* __restrict__ ssq_part)
{
    const int kq = blockIdx.x, cg = blockIdx.y, b = blockIdx.z;
    const int c0 = cg * 32;
    const int t = threadIdx.x;
    const int kl = t >> 2, cq = t & 3;
    uint e = sorted[b * Kk + kq * 64 + kl];
    int hw = (int)(e >> 10), k = (int)(e & 1023u);
    const float* xp = x + (size_t)(b * Cc + c0 + cq * 8) * HWp + hw;
    float v[8];
    #pragma unroll
    for (int j = 0; j < 8; ++j) v[j] = xp[(size_t)j * HWp];

    ushort ev[8]; float s2 = 0.f;
    #pragma unroll
    for (int j = 0; j < 8; ++j) {
        ev[j] = __hip_bfloat16_raw(__float2bfloat16(v[j])).x;
        float f = __uint_as_float((uint)ev[j] << 16);
        s2 += f * f;
    }
    s2 += __shfl_xor(s2, 1);
    s2 += __shfl_xor(s2, 2);                // sum over the 4 cq-lanes

    uint4 o = make_uint4((uint)ev[0] | ((uint)ev[1] << 16),
                         (uint)ev[2] | ((uint)ev[3] << 16),
                         (uint)ev[4] | ((uint)ev[5] << 16),
                         (uint)ev[6] | ((uint)ev[7] << 16));
    *(uint4*)((ushort*)embr + (size_t)(b * Kk + k) * Cc + c0 + cq * 8) = o;
    if (cq == 0)
        ssq_part[cg * BK + b * Kk + k] = s2;
}

// ---------------------------------------------------------------------------
// K2: Gram (verbatim R13 MFMA core + epilogue) + tiny scl preamble:
// 256 threads each sum the 8 ssq partials of one of the block's 256 rows
// (8 KB/block, L2-resident; 30x lighter than R15's full-row recompute) ->
// scl_i/scl_j in LDS.  Fixed summation order c=0..7 -> every block computes
// bitwise-identical scl; duplicate rows -> identical scl -> d2_dup ~ 0.
// d2 = 200 - 2*scl_i*scl_j*Graw, clamped >= 0 BEFORE the uint-bit atomicMin.
// ---------------------------------------------------------------------------
__global__ __launch_bounds__(256) void gram_mfma_min(
    const __hip_bfloat16* __restrict__ emb, const float* __restrict__ ssq_part,
    const int* __restrict__ mask, unsigned* __restrict__ neg)
{
    __shared__ __align__(16) short As[TILE * 64];   // 16 KB
    __shared__ __align__(16) short Bs[TILE * 64];   // 16 KB
    __shared__ float scl_i[TILE], scl_j[TILE];      // 1 KB
    int b  = blockIdx.z;
    int i0 = blockIdx.y * TILE;
    int j0 = blockIdx.x * TILE;
    int tid = threadIdx.x;
    int w  = tid >> 6, l = tid & 63;
    int wr = w >> 1, wc = w & 1;          // wave's 64x64 quadrant
    int lr = l & 15, lg = l >> 4;         // lane row / k-group

    // ---- preamble: scl for the block's 128 i-rows and 128 j-rows ---------
    {
        int m  = tid >> 7;                 // 0 = i-panel, 1 = j-panel
        int rl = tid & 127;
        int grow = b * Kk + (m ? j0 : i0) + rl;
        float s2 = 0.f;
        #pragma unroll
        for (int c = 0; c < 8; ++c) s2 += ssq_part[c * BK + grow];
        float sc = 10.0f / fmaxf(sqrtf(s2), 1e-12f);
        if (m) scl_j[rl] = sc; else scl_i[rl] = sc;
    }
    // (first k-loop __syncthreads orders these writes before epilogue reads)

    const short* E  = (const short*)emb + (size_t)b * Kk * Cc;
    const short* EA = E + (size_t)i0 * Cc;
    const short* EB = E + (size_t)j0 * Cc;

    // staging: instr t (=w*4+q) fills LDS rows t*8..t*8+7; lane l ->
    // row offset l/8, slot l%8; source k-chunk = (l%8) ^ (l/8).
    const int lrow = l >> 3;
    const int lsub = (l & 7) ^ lrow;

    f32x4 acc[4][4] = {};
    for (int k0 = 0; k0 < Cc; k0 += 64) {
        #pragma unroll
        for (int q = 0; q < 4; ++q) {
            int t = w * 4 + q;
            int r = t * 8 + lrow;
            __builtin_amdgcn_global_load_lds(
                (const __attribute__((address_space(1))) void*)(EA + (size_t)r * Cc + k0 + lsub * 8),
                (__attribute__((address_space(3))) void*)&As[t * 512], 16, 0, 0);
            __builtin_amdgcn_global_load_lds(
                (const __attribute__((address_space(1))) void*)(EB + (size_t)r * Cc + k0 + lsub * 8),
                (__attribute__((address_space(3))) void*)&Bs[t * 512], 16, 0, 0);
        }
        __syncthreads();

        #pragma unroll
        for (int kk = 0; kk < 2; ++kk) {
            bf16x8 af[4], bf[4];
            #pragma unroll
            for (int f = 0; f < 4; ++f) {
                int ra = wr * 64 + f * 16 + lr;
                af[f] = *(const bf16x8*)&As[ra * 64 + (((kk * 4 + lg) ^ (ra & 7)) << 3)];
                int rb = wc * 64 + f * 16 + lr;
                bf[f] = *(const bf16x8*)&Bs[rb * 64 + (((kk * 4 + lg) ^ (rb & 7)) << 3)];
            }
            #pragma unroll
            for (int fi = 0; fi < 4; ++fi)
                #pragma unroll
                for (int fj = 0; fj < 4; ++fj)
                    acc[fi][fj] = __builtin_amdgcn_mfma_f32_16x16x32_bf16(
                                      af[fi], bf[fj], acc[fi][fj], 0, 0, 0);
        }
        __syncthreads();
    }

    const int* mb = mask + b * Kk;
    float cjv[4]; int jgv[4]; bool jva[4];
    #pragma unroll
    for (int fj = 0; fj < 4; ++fj) {
        int jl = wc * 64 + fj * 16 + lr;
        jgv[fj] = j0 + jl;
        cjv[fj] = scl_j[jl];
        jva[fj] = (mb[j0 + jl] != 0);
    }
    #pragma unroll
    for (int fi = 0; fi < 4; ++fi) {
        #pragma unroll
        for (int r = 0; r < 4; ++r) {
            int il = wr * 64 + fi * 16 + 4 * lg + r;
            int ig = i0 + il;
            float ci = scl_i[il];
            float m = BIGF;
            #pragma unroll
            for (int fj = 0; fj < 4; ++fj) {
                float d2 = fmaxf(200.0f - 2.0f * ci * cjv[fj] * acc[fi][fj][r], 0.0f);
                bool ok = jva[fj] && (jgv[fj] != ig);
                m = ok ? fminf(m, d2) : m;
            }
            #pragma unroll
            for (int off = 1; off < 16; off <<= 1)
                m = fminf(m, __shfl_xor(m, off));
            if (lr == 0)
                atomicMin(&neg[b * Kk + ig], __float_as_uint(m));
        }
    }
}

// ---------------------------------------------------------------------------
// K3: hinge + mean (verbatim R13, proven).
// ---------------------------------------------------------------------------
__global__ __launch_bounds__(1024) void hinge_final(
    const unsigned* __restrict__ neg, const int* __restrict__ mask,
    float* __restrict__ out)
{
    float h = 0.f, v = 0.f;
    for (int i = threadIdx.x; i < BK; i += 1024) {
        if (mask[i] != 0) {
            float d = sqrtf(__uint_as_float(neg[i]));
            h += fmaxf(MARGIN_F - d, 0.f);
            v += 1.f;
        }
    }
    #pragma unroll
    for (int off = 32; off; off >>= 1) {
        h += __shfl_xor(h, off);
        v += __shfl_xor(v, off);
    }
    __shared__ float sh[16], sv[16];
    int w = threadIdx.x >> 6;
    if ((threadIdx.x & 63) == 0) { sh[w] = h; sv[w] = v; }
    __syncthreads();
    if (threadIdx.x == 0) {
        float H = 0.f, V = 0.f;
        #pragma unroll
        for (int i = 0; i < 16; ++i) { H += sh[i]; V += sv[i]; }
        out[0] = H / V;
    }
}

// ---------------------------------------------------------------------------
extern "C" void kernel_launch(void* const* d_in, const int* in_sizes, int n_in,
                              void* d_out, int out_size, void* d_ws, size_t ws_size,
                              hipStream_t stream) {
    const float* x    = (const float*)d_in[0];   // [B,C,H,W] fp32
    const int*   ind  = (const int*)d_in[1];     // [B,K] int32
    const int*   mask = (const int*)d_in[2];     // [B,K] int32
    float* out = (float*)d_out;

    // ws layout: embr bf16 [B*K][C] (4 MB) | ssq_part f32 [8][B*K] (256 KB)
    //            | neg u32 [B*K] | sorted u32 [B*K]
    __hip_bfloat16* embr = (__hip_bfloat16*)d_ws;
    float*    ssq_part = (float*)((char*)d_ws + (size_t)BK * Cc * sizeof(__hip_bfloat16));
    unsigned* neg    = (unsigned*)(ssq_part + 8 * BK);
    uint*     sorted = (uint*)(neg + BK);

    bucket_sort<<<Bz, 1024, 0, stream>>>(ind, sorted, neg);
    dim3 g1(16, Cc / 32, Bz);                 // (16 kq, 8 cgroups, 8 b)
    sorted_gather<<<g1, 256, 0, stream>>>(x, sorted, embr, ssq_part);
    dim3 g2(Kk / TILE, Kk / TILE, Bz);
    gram_mfma_min<<<g2, 256, 0, stream>>>(embr, ssq_part, mask, neg);
    hinge_final<<<1, 1024, 0, stream>>>(neg, mask, out);
}

// Round 19
// 49.233 us; speedup vs baseline: 1.8203x; 1.0394x over previous
//
#include <hip/hip_runtime.h>
#include <hip/hip_bf16.h>

// Problem constants (fixed by the reference)
#define Bz 8
#define Cc 256
#define HWp 23104            // 152*152
#define Kk 1024
#define BK (Bz*Kk)
#define MARGIN_F 10.0f
#define BIGF 1e30f
#define TILE 128
#define NBK 128              // buckets (hw>>8 in [0,90], padded to 128)

typedef __attribute__((ext_vector_type(8))) short bf16x8;  // 8 bf16 = 4 VGPRs
typedef __attribute__((ext_vector_type(4))) float f32x4;   // MFMA 16x16 accumulator

// ---------------------------------------------------------------------------
// K0: per-batch BUCKET sort (R13/R17 core) with PARALLEL Hillis-Steele
// prefix (replaces the 128-iter serial loop by thread 0, ~1-2us saved).
// Intra-bucket order is timing-dependent but every downstream output byte is
// order-independent (each k writes only its own embr row; min is exact).
// Also inits neg_min + acc + cnt (ws poisoned once; cnt ends each launch at
// 32 and is re-zeroed here -> graph-replay safe).
// ---------------------------------------------------------------------------
__global__ __launch_bounds__(1024) void bucket_sort(
    const int* __restrict__ ind, uint* __restrict__ sorted,
    unsigned* __restrict__ neg, float* __restrict__ acc,
    unsigned* __restrict__ cnt)
{
    __shared__ uint cur[NBK], pre[NBK];
    const int b = blockIdx.x, tid = threadIdx.x;
    if (tid < NBK) cur[tid] = 0;
    neg[b * Kk + tid] = __float_as_uint(BIGF);
    if (b == 0 && tid < 2) acc[tid] = 0.f;
    if (b == 0 && tid == 0) *cnt = 0u;
    __syncthreads();
    int hw = ind[b * Kk + tid];
    int bk = hw >> 8;                       // 0..90
    atomicAdd(&cur[bk], 1u);
    __syncthreads();
    uint mycount = (tid < NBK) ? cur[tid] : 0u;
    if (tid < NBK) pre[tid] = mycount;
    __syncthreads();
    #pragma unroll
    for (int off = 1; off < NBK; off <<= 1) {   // inclusive scan, 7 steps
        uint add = (tid < NBK && tid >= off) ? pre[tid - off] : 0u;
        __syncthreads();
        if (tid < NBK) pre[tid] += add;
        __syncthreads();
    }
    if (tid < NBK) cur[tid] = pre[tid] - mycount;   // exclusive cursor
    __syncthreads();
    uint slot = atomicAdd(&cur[bk], 1u);    // unique slot within bucket
    sorted[b * Kk + slot] = ((uint)hw << 10) | (uint)tid;
}

// ---------------------------------------------------------------------------
// K1: sorted gather + fused ssq partials (VERBATIM R17, proven).
// Thread t: entry kl = t>>2, octet cq = t&3; 8 independent loads/thread;
// 2x shfl_xor -> 32-channel ssq partial; cq==0 stores ssq_part[cg][row].
// embr writes: ONE full 64B line per k, exactly once.
// ---------------------------------------------------------------------------
__global__ __launch_bounds__(256) void sorted_gather(
    const float* __restrict__ x, const uint* __restrict__ sorted,
    __hip_bfloat16* __restrict__ embr, float* __restrict__ ssq_part)
{
    const int kq = blockIdx.x, cg = blockIdx.y, b = blockIdx.z;
    const int c0 = cg * 32;
    const int t = threadIdx.x;
    const int kl = t >> 2, cq = t & 3;
    uint e = sorted[b * Kk + kq * 64 + kl];
    int hw = (int)(e >> 10), k = (int)(e & 1023u);
    const float* xp = x + (size_t)(b * Cc + c0 + cq * 8) * HWp + hw;
    float v[8];
    #pragma unroll
    for (int j = 0; j < 8; ++j) v[j] = xp[(size_t)j * HWp];

    ushort ev[8]; float s2 = 0.f;
    #pragma unroll
    for (int j = 0; j < 8; ++j) {
        ev[j] = __hip_bfloat16_raw(__float2bfloat16(v[j])).x;
        float f = __uint_as_float((uint)ev[j] << 16);
        s2 += f * f;
    }
    s2 += __shfl_xor(s2, 1);
    s2 += __shfl_xor(s2, 2);                // sum over the 4 cq-lanes

    uint4 o = make_uint4((uint)ev[0] | ((uint)ev[1] << 16),
                         (uint)ev[2] | ((uint)ev[3] << 16),
                         (uint)ev[4] | ((uint)ev[5] << 16),
                         (uint)ev[6] | ((uint)ev[7] << 16));
    *(uint4*)((ushort*)embr + (size_t)(b * Kk + k) * Cc + c0 + cq * 8) = o;
    if (cq == 0)
        ssq_part[cg * BK + b * Kk + k] = s2;
}

// ---------------------------------------------------------------------------
// K2: Gram + scl preamble from ssq partials (VERBATIM R17, proven).
// d2 = 200 - 2*scl_i*scl_j*Graw, clamped >= 0 BEFORE the uint-bit atomicMin
// (duplicate-index pairs = the loss signal; identical rows -> identical scl).
// ---------------------------------------------------------------------------
__global__ __launch_bounds__(256) void gram_mfma_min(
    const __hip_bfloat16* __restrict__ emb, const float* __restrict__ ssq_part,
    const int* __restrict__ mask, unsigned* __restrict__ neg)
{
    __shared__ __align__(16) short As[TILE * 64];   // 16 KB
    __shared__ __align__(16) short Bs[TILE * 64];   // 16 KB
    __shared__ float scl_i[TILE], scl_j[TILE];      // 1 KB
    int b  = blockIdx.z;
    int i0 = blockIdx.y * TILE;
    int j0 = blockIdx.x * TILE;
    int tid = threadIdx.x;
    int w  = tid >> 6, l = tid & 63;
    int wr = w >> 1, wc = w & 1;          // wave's 64x64 quadrant
    int lr = l & 15, lg = l >> 4;         // lane row / k-group

    // ---- preamble: scl for the block's 128 i-rows and 128 j-rows ---------
    {
        int m  = tid >> 7;                 // 0 = i-panel, 1 = j-panel
        int rl = tid & 127;
        int grow = b * Kk + (m ? j0 : i0) + rl;
        float s2 = 0.f;
        #pragma unroll
        for (int c = 0; c < 8; ++c) s2 += ssq_part[c * BK + grow];
        float sc = 10.0f / fmaxf(sqrtf(s2), 1e-12f);
        if (m) scl_j[rl] = sc; else scl_i[rl] = sc;
    }
    // (first k-loop __syncthreads orders these writes before epilogue reads)

    const short* E  = (const short*)emb + (size_t)b * Kk * Cc;
    const short* EA = E + (size_t)i0 * Cc;
    const short* EB = E + (size_t)j0 * Cc;

    // staging: instr t (=w*4+q) fills LDS rows t*8..t*8+7; lane l ->
    // row offset l/8, slot l%8; source k-chunk = (l%8) ^ (l/8).
    const int lrow = l >> 3;
    const int lsub = (l & 7) ^ lrow;

    f32x4 acc[4][4] = {};
    for (int k0 = 0; k0 < Cc; k0 += 64) {
        #pragma unroll
        for (int q = 0; q < 4; ++q) {
            int t = w * 4 + q;
            int r = t * 8 + lrow;
            __builtin_amdgcn_global_load_lds(
                (const __attribute__((address_space(1))) void*)(EA + (size_t)r * Cc + k0 + lsub * 8),
                (__attribute__((address_space(3))) void*)&As[t * 512], 16, 0, 0);
            __builtin_amdgcn_global_load_lds(
                (const __attribute__((address_space(1))) void*)(EB + (size_t)r * Cc + k0 + lsub * 8),
                (__attribute__((address_space(3))) void*)&Bs[t * 512], 16, 0, 0);
        }
        __syncthreads();

        #pragma unroll
        for (int kk = 0; kk < 2; ++kk) {
            bf16x8 af[4], bf[4];
            #pragma unroll
            for (int f = 0; f < 4; ++f) {
                int ra = wr * 64 + f * 16 + lr;
                af[f] = *(const bf16x8*)&As[ra * 64 + (((kk * 4 + lg) ^ (ra & 7)) << 3)];
                int rb = wc * 64 + f * 16 + lr;
                bf[f] = *(const bf16x8*)&Bs[rb * 64 + (((kk * 4 + lg) ^ (rb & 7)) << 3)];
            }
            #pragma unroll
            for (int fi = 0; fi < 4; ++fi)
                #pragma unroll
                for (int fj = 0; fj < 4; ++fj)
                    acc[fi][fj] = __builtin_amdgcn_mfma_f32_16x16x32_bf16(
                                      af[fi], bf[fj], acc[fi][fj], 0, 0, 0);
        }
        __syncthreads();
    }

    const int* mb = mask + b * Kk;
    float cjv[4]; int jgv[4]; bool jva[4];
    #pragma unroll
    for (int fj = 0; fj < 4; ++fj) {
        int jl = wc * 64 + fj * 16 + lr;
        jgv[fj] = j0 + jl;
        cjv[fj] = scl_j[jl];
        jva[fj] = (mb[j0 + jl] != 0);
    }
    #pragma unroll
    for (int fi = 0; fi < 4; ++fi) {
        #pragma unroll
        for (int r = 0; r < 4; ++r) {
            int il = wr * 64 + fi * 16 + 4 * lg + r;
            int ig = i0 + il;
            float ci = scl_i[il];
            float m = BIGF;
            #pragma unroll
            for (int fj = 0; fj < 4; ++fj) {
                float d2 = fmaxf(200.0f - 2.0f * ci * cjv[fj] * acc[fi][fj][r], 0.0f);
                bool ok = jva[fj] && (jgv[fj] != ig);
                m = ok ? fminf(m, d2) : m;
            }
            #pragma unroll
            for (int off = 1; off < 16; off <<= 1)
                m = fminf(m, __shfl_xor(m, off));
            if (lr == 0)
                atomicMin(&neg[b * Kk + ig], __float_as_uint(m));
        }
    }
}

// ---------------------------------------------------------------------------
// K3: hinge + mean, DISTRIBUTED: 32 blocks x 256 threads (one row/thread,
// CU-parallel; the old single block left 248 CUs idle).  Tail: per-block
// atomicAdd into acc[2]; elected-last via acq_rel fetch_add on cnt (32
// fences total -- 16x below the R15 poison scale); winner reads exactly 2
// coherent RMWs and writes out.
// ---------------------------------------------------------------------------
__global__ __launch_bounds__(256) void hinge_final(
    const unsigned* __restrict__ neg, const int* __restrict__ mask,
    float* __restrict__ acc, unsigned* __restrict__ cnt,
    float* __restrict__ out)
{
    const int tid = threadIdx.x;
    const int i = blockIdx.x * 256 + tid;
    float h = 0.f, v = 0.f;
    if (mask[i] != 0) {
        float d = sqrtf(__uint_as_float(neg[i]));
        h = fmaxf(MARGIN_F - d, 0.f);
        v = 1.f;
    }
    #pragma unroll
    for (int off = 32; off; off >>= 1) {
        h += __shfl_xor(h, off);
        v += __shfl_xor(v, off);
    }
    __shared__ float sh[4], sv[4];
    int w = tid >> 6;
    if ((tid & 63) == 0) { sh[w] = h; sv[w] = v; }
    __syncthreads();
    if (tid == 0) {
        atomicAdd(&acc[0], sh[0] + sh[1] + sh[2] + sh[3]);
        atomicAdd(&acc[1], sv[0] + sv[1] + sv[2] + sv[3]);
        unsigned prev = __hip_atomic_fetch_add(cnt, 1u, __ATOMIC_ACQ_REL,
                                               __HIP_MEMORY_SCOPE_AGENT);
        if (prev == 31u) {
            float H = atomicAdd(&acc[0], 0.0f);   // coherent RMW reads (2)
            float V = atomicAdd(&acc[1], 0.0f);
            out[0] = H / V;
        }
    }
}

// ---------------------------------------------------------------------------
extern "C" void kernel_launch(void* const* d_in, const int* in_sizes, int n_in,
                              void* d_out, int out_size, void* d_ws, size_t ws_size,
                              hipStream_t stream) {
    const float* x    = (const float*)d_in[0];   // [B,C,H,W] fp32
    const int*   ind  = (const int*)d_in[1];     // [B,K] int32
    const int*   mask = (const int*)d_in[2];     // [B,K] int32
    float* out = (float*)d_out;

    // ws layout: embr bf16 [B*K][C] (4 MB) | ssq_part f32 [8][B*K] (256 KB)
    //            | neg u32 [B*K] | sorted u32 [B*K] | acc f32[2] | cnt u32
    __hip_bfloat16* embr = (__hip_bfloat16*)d_ws;
    float*    ssq_part = (float*)((char*)d_ws + (size_t)BK * Cc * sizeof(__hip_bfloat16));
    unsigned* neg    = (unsigned*)(ssq_part + 8 * BK);
    uint*     sorted = (uint*)(neg + BK);
    float*    acc    = (float*)(sorted + BK);
    unsigned* cnt    = (unsigned*)(acc + 2);

    bucket_sort<<<Bz, 1024, 0, stream>>>(ind, sorted, neg, acc, cnt);
    dim3 g1(16, Cc / 32, Bz);                 // (16 kq, 8 cgroups, 8 b)
    sorted_gather<<<g1, 256, 0, stream>>>(x, sorted, embr, ssq_part);
    dim3 g2(Kk / TILE, Kk / TILE, Bz);
    gram_mfma_min<<<g2, 256, 0, stream>>>(embr, ssq_part, mask, neg);
    hinge_final<<<32, 256, 0, stream>>>(neg, mask, acc, cnt, out);
}